// Round 8
// baseline (4825.176 us; speedup 1.0000x reference)
//
#include <hip/hip_runtime.h>

#define BB 16
#define NN 2048
#define NITERS 100

// k = log2(e)/eps, eps = 0.05
#define K2E      28.853900817779268f
#define TWO_K2E  57.707801635558536f
#define INV2K    0.017328679513998632f   // 1/(2k)
#define INV_K2E  0.034657359027997264f
#define INV4K    0.008664339756999316f   // 1/(4k)
#define LMU      (-11.0f)                // log2(1/2048)

#if __has_builtin(__builtin_amdgcn_exp2f)
#define EXP2F(x) __builtin_amdgcn_exp2f(x)
#else
#define EXP2F(x) exp2f(x)
#endif

typedef float v2f __attribute__((ext_vector_type(2)));
typedef float v4f __attribute__((ext_vector_type(4)));

// device-coherent (LLC-homed) accessors for the dual arrays
#define DSTORE(p, v) __hip_atomic_store((p), (v), __ATOMIC_RELAXED, __HIP_MEMORY_SCOPE_AGENT)
#define DLOAD(p)     __hip_atomic_load((p), __ATOMIC_RELAXED, __HIP_MEMORY_SCOPE_AGENT)

// force a wave-uniform float into an SGPR (hipcc can't prove tid>>6-derived
// LDS reads uniform; readfirstlane result is uniform by definition)
__device__ __forceinline__ float rfl(float x) {
    return __int_as_float(__builtin_amdgcn_readfirstlane(__float_as_int(x)));
}

// verified multi-value butterfly (R3/R5/R8): 8 partials -> full row-sum on
// lanes 0..7 at row index rr = ((lane&1)<<2)|(lane&2)|((lane>>2)&1)
__device__ __forceinline__ float bfly8(const float acc[8], int lane) {
    const bool b0 = lane & 1, b1 = lane & 2, b2 = lane & 4;
    float v4[4], v2_[2], v1;
    #pragma unroll
    for (int i = 0; i < 4; ++i) {
        float recv = __shfl_xor(b0 ? acc[i] : acc[i+4], 1, 64);
        v4[i] = (b0 ? acc[i+4] : acc[i]) + recv;
    }
    #pragma unroll
    for (int i = 0; i < 2; ++i) {
        float recv = __shfl_xor(b1 ? v4[i] : v4[i+2], 2, 64);
        v2_[i] = (b1 ? v4[i+2] : v4[i]) + recv;
    }
    {
        float recv = __shfl_xor(b2 ? v2_[0] : v2_[1], 4, 64);
        v1 = (b2 ? v2_[1] : v2_[0]) + recv;
    }
    v1 += __shfl_xor(v1, 8, 64);
    v1 += __shfl_xor(v1, 16, 64);
    v1 += __shfl_xor(v1, 32, 64);
    return v1;
}

// R19 FUSED sum-pass: both batches' passes interleaved in one s-loop.
//  - 16 independent fma->exp->acc chains per wave (8 rows x 2 batches):
//    fills trans/dependency bubbles that 4 waves/SIMD can't.
//  - xp row-coords are wave-uniform -> readfirstlane into SGPRs: each FMA
//    is v_fma_f32 with 1 SGPR operand (legal), no v2f broadcast movs.
//  - scalar fma (packed f32 has no throughput advantage on CDNA).
//  - 32 LLC dual preloads (16/batch) in flight across the pass.
// Returns combined row-sums for both batches on lanes 0..7.
__device__ __forceinline__ void sumpass2(
    const v4f* __restrict__ U0, const v4f* __restrict__ T0,
    const float* __restrict__ g0,
    const v4f* __restrict__ U1, const v4f* __restrict__ T1,
    const float* __restrict__ g1,
    int rloc, int jh, int lane, int w, float* pcomb,
    float* pS0, float* pS1)
{
    const int jb = (jh << 10) + lane;
    float dv0[16], dv1[16];
    #pragma unroll
    for (int s = 0; s < 16; ++s) dv0[s] = DLOAD(g0 + jb + (s << 6));
    #pragma unroll
    for (int s = 0; s < 16; ++s) dv1[s] = DLOAD(g1 + jb + (s << 6));

    // wave-uniform row coords -> SGPRs (computed once per pass)
    float xa0[8], xa1[8], xa2[8], xb0[8], xb1[8], xb2[8];
    #pragma unroll
    for (int k = 0; k < 8; ++k) {
        const v4f ua = U0[rloc + k];
        xa0[k] = rfl(ua.x * INV2K); xa1[k] = rfl(ua.y * INV2K); xa2[k] = rfl(ua.z * INV2K);
        const v4f ub = U1[rloc + k];
        xb0[k] = rfl(ub.x * INV2K); xb1[k] = rfl(ub.y * INV2K); xb2[k] = rfl(ub.z * INV2K);
    }
    float acc0[8], acc1[8];
    #pragma unroll
    for (int k = 0; k < 8; ++k) { acc0[k] = 0.f; acc1[k] = 0.f; }

    #pragma unroll 4
    for (int s = 0; s < 16; ++s) {
        const int p = jb + (s << 6);
        const v4f ta = T0[p];
        const v4f tb = T1[p];
        const float ad0 = dv0[s], ad1 = dv1[s];
        #pragma unroll
        for (int k = 0; k < 8; ++k) {
            float d0 = fmaf(xa0[k], ta.x, fmaf(xa1[k], ta.y, fmaf(xa2[k], ta.z, ad0)));
            acc0[k] += EXP2F(d0);
        }
        #pragma unroll
        for (int k = 0; k < 8; ++k) {
            float d1 = fmaf(xb0[k], tb.x, fmaf(xb1[k], tb.y, fmaf(xb2[k], tb.z, ad1)));
            acc1[k] += EXP2F(d1);
        }
    }
    float r0 = bfly8(acc0, lane);
    float r1 = bfly8(acc1, lane);
    const int rr = ((lane & 1) << 2) | (lane & 2) | ((lane >> 2) & 1);
    if (lane < 8) { pcomb[w * 8 + rr] = r0; pcomb[128 + w * 8 + rr] = r1; }
    __syncthreads();
    float S0 = 0.f, S1 = 0.f;
    if (lane < 8) {
        S0 = r0 + pcomb[(w ^ 1) * 8 + rr];
        S1 = r1 + pcomb[128 + (w ^ 1) * 8 + rr];
    }
    *pS0 = S0; *pS1 = S1;
}

// Epilogue partial: sum_j P_ij*C_ij, 8 rows x own j-half; AoS tables.
// (verified in R7 — runs once, ~1% of runtime)
__device__ __forceinline__ float epilA(
    const v4f* __restrict__ U, const v4f* __restrict__ T,
    const float* __restrict__ gB,
    float Aval, int rloc, int jh, int lane)
{
    const int jb = (jh << 10) + lane;
    float dv[16];
    #pragma unroll
    for (int s = 0; s < 16; ++s)
        dv[s] = DLOAD(gB + jb + (s << 6));

    float xr0[8], xr1[8], xr2[8], Ak[8], x2k[8];
    #pragma unroll
    for (int k = 0; k < 8; ++k) {
        const v4f u = U[rloc + k];
        xr0[k] = u.x * INV2K;
        xr1[k] = u.y * INV2K;
        xr2[k] = u.z * INV2K;
        const int src = ((k & 1) << 2) | (k & 2) | ((k >> 2) & 1);
        Ak[k]  = __shfl(Aval, src, 64);
        x2k[k] = K2E * (xr0[k]*xr0[k] + xr1[k]*xr1[k] + xr2[k]*xr2[k]);
    }
    float acc = 0.f;
    for (int s = 0; s < 16; ++s) {
        const v4f t = T[jb + (s << 6)];
        const float a0 = t.x, a1 = t.y, a2 = t.z, tb = dv[s];
        const float q2 = (a0*a0 + a1*a1 + a2*a2) * INV4K;   // k|y|^2
        #pragma unroll
        for (int k = 0; k < 8; ++k) {
            float d = fmaf(xr0[k], a0, fmaf(xr1[k], a1, fmaf(xr2[k], a2, tb)));
            float P = EXP2F(d + Ak[k]);                       // exp(logP)
            float C = fmaxf((x2k[k] + q2 - (d - tb)) * INV_K2E, 0.f);
            acc = fmaf(P, C, acc);
        }
    }
    return acc;
}

// R19: fused 2-phase schedule. 256 blocks x 1024 threads (1/CU), 128 KB AoS
// LDS (R7-verified), lb(1024,4) VGPR budget (R7-verified harmless).
// Per iteration: fusedF {fA0+fA1} -> PW -> fusedG {gB0+gB1} -> PW.
// ONE flag array per pair (32 slots); values 1, 2it+2, 2it+3 monotonic.
// Waits are zero-slack (post phase p, wait all peers >= p) — traded for
// 2x per-wave ILP and half the sync tails.
__global__ __launch_bounds__(1024, 4) void emd_sinkhornZ(
    const float* __restrict__ x, const float* __restrict__ y,
    float* __restrict__ Af, float* __restrict__ Bf,
    int* __restrict__ flags, float* __restrict__ out)
{
    extern __shared__ float S[];     // 4 * NN * 4 floats = 128 KB
    __shared__ float pcomb[2 * 128];
    __shared__ float wsum[16];

    const int tid  = threadIdx.x;
    const int lane = tid & 63;
    const int w    = tid >> 6;        // 0..15
    const int pr   = w >> 1;          // wave-pair 0..7
    const int jh   = w & 1;           // j-half
    const int blk  = blockIdx.x;
    const int pair = blk & 7;         // = XCD id under round-robin (perf only)
    const int q    = blk >> 3;        // 0..31: row-slice within pair
    const int b0   = pair * 2, b1 = b0 + 1;
    const int base0 = b0 * NN, base1 = b1 * NN;
    const int rloc  = q * 64 + pr * 8;      // within-batch row base
    int* fp = flags + pair * 128;     // ONE array per pair: 32 slots x 16 B

    v4f *sy0 = (v4f*)S;               // batch0 y (2k-scaled, AoS)
    v4f *sx0 = (v4f*)S + 1*NN;        // batch0 x
    v4f *sy1 = (v4f*)S + 2*NN;        // batch1 y
    v4f *sx1 = (v4f*)S + 3*NN;        // batch1 x

    // ---- prologue: stage 2k-scaled AoS tables ----
    #pragma unroll
    for (int v = 0; v < 2; ++v) {
        const int p = tid + (v << 10);
        {
            const float* px = x + 3 * (size_t)(base0 + p);
            sx0[p] = (v4f){TWO_K2E * px[0], TWO_K2E * px[1], TWO_K2E * px[2], 0.f};
            const float* py = y + 3 * (size_t)(base0 + p);
            sy0[p] = (v4f){TWO_K2E * py[0], TWO_K2E * py[1], TWO_K2E * py[2], 0.f};
        }
        {
            const float* px = x + 3 * (size_t)(base1 + p);
            sx1[p] = (v4f){TWO_K2E * px[0], TWO_K2E * px[1], TWO_K2E * px[2], 0.f};
            const float* py = y + 3 * (size_t)(base1 + p);
            sy1[p] = (v4f){TWO_K2E * py[0], TWO_K2E * py[1], TWO_K2E * py[2], 0.f};
        }
    }
    // ---- prologue: B0-init for own 64 columns of both batches ----
    if (tid < 128) {
        const int bb  = tid >> 6;
        const int col = q * 64 + (tid & 63);
        const int bs  = bb ? base1 : base0;
        const float* py = y + 3 * (size_t)(bs + col);
        const float a = py[0], b = py[1], c = py[2];
        DSTORE(&Bf[bs + col], -K2E * (a*a + b*b + c*c));
    }
    __syncthreads();                  // drains table + B-init stores
    if (tid == 0)
        __hip_atomic_store(fp + q * 4, 1, __ATOMIC_RELEASE, __HIP_MEMORY_SCOPE_AGENT);

    // post own phase into own slot + wait all 32 slots (same array)
    #define PW(pval, tgt) do { __syncthreads();                                 \
        if (tid == 0)                                                           \
            __hip_atomic_store(fp + q * 4, (pval), __ATOMIC_RELEASE,            \
                               __HIP_MEMORY_SCOPE_AGENT);                       \
        if (w == 0) {                                                           \
            for (;;) {                                                          \
                int vv = (lane < 32)                                            \
                    ? __hip_atomic_load(fp + lane * 4, __ATOMIC_RELAXED,        \
                                        __HIP_MEMORY_SCOPE_AGENT)               \
                    : 0x7fffffff;                                               \
                if (__ballot(vv >= (tgt)) == ~0ULL) break;                      \
                __builtin_amdgcn_s_sleep(1);                                    \
            }                                                                   \
        }                                                                       \
        __syncthreads(); } while (0)

    #define WONLY(tgt) do { __syncthreads();                                    \
        if (w == 0) {                                                           \
            for (;;) {                                                          \
                int vv = (lane < 32)                                            \
                    ? __hip_atomic_load(fp + lane * 4, __ATOMIC_RELAXED,        \
                                        __HIP_MEMORY_SCOPE_AGENT)               \
                    : 0x7fffffff;                                               \
                if (__ballot(vv >= (tgt)) == ~0ULL) break;                      \
                __builtin_amdgcn_s_sleep(1);                                    \
            }                                                                   \
        }                                                                       \
        __syncthreads(); } while (0)

    WONLY(1);                         // all B-inits of the pair visible

    const int rr = ((lane & 1) << 2) | (lane & 2) | ((lane >> 2) & 1);
    float Aval0 = 0.f, Aval1 = 0.f;

    for (int it = 0; it < NITERS; ++it) {
        // ---- fused f: fA0 + fA1 (duals = Bf, complete by prior wait) ----
        {
            float S0, S1;
            sumpass2(sx0, sy0, Bf + base0, sx1, sy1, Bf + base1,
                     rloc, jh, lane, w, pcomb, &S0, &S1);
            Aval0 = LMU - __log2f(S0);
            Aval1 = LMU - __log2f(S1);
            if (lane < 8 && jh == 0) {
                DSTORE(&Af[base0 + rloc + rr], Aval0);
                DSTORE(&Af[base1 + rloc + rr], Aval1);
            }
        }
        PW(2 * it + 2, 2 * it + 2);   // post f; wait all peers' f
        // ---- fused g: gB0 + gB1 (duals = Af) ----
        {
            float S0, S1;
            sumpass2(sy0, sx0, Af + base0, sy1, sx1, Af + base1,
                     rloc, jh, lane, w, pcomb, &S0, &S1);
            if (lane < 8 && jh == 0) {
                DSTORE(&Bf[base0 + rloc + rr], LMU - __log2f(S0));
                DSTORE(&Bf[base1 + rloc + rr], LMU - __log2f(S1));
            }
        }
        PW(2 * it + 3, 2 * it + 3);   // post g; wait all peers' g
    }
    // last PW (201) already guarantees final Bf complete for the epilogue

    // ---- epilogue: own 64 rows of each batch, own j-half ----
    {
        float s = epilA(sx0, sy0, Bf + base0, Aval0, rloc, jh, lane)
                + epilA(sx1, sy1, Bf + base1, Aval1, rloc, jh, lane);
        #pragma unroll
        for (int m = 32; m > 0; m >>= 1) s += __shfl_xor(s, m, 64);
        if (lane == 0) wsum[w] = s;
        __syncthreads();
        if (tid == 0) {
            float t = 0.f;
            #pragma unroll
            for (int i = 0; i < 16; ++i) t += wsum[i];
            atomicAdd(out, t * (1.0f / (float)BB));
        }
    }
    #undef PW
    #undef WONLY
}

// =============== verified R18/R7 AoS kernel (launch fallback) ===============
__device__ __forceinline__ float sumpassA(
    const v4f* __restrict__ U, const v4f* __restrict__ T,
    const float* __restrict__ gd,
    int rloc, int jh, int lane, int w, float* pcomb)
{
    const int jb = (jh << 10) + lane;
    float dv[16];
    #pragma unroll
    for (int s = 0; s < 16; ++s)
        dv[s] = DLOAD(gd + jb + (s << 6));

    v2f xp0[4], xp1[4], xp2[4], acc2[4];
    #pragma unroll
    for (int p = 0; p < 4; ++p) {
        const v4f ua = U[rloc + 2*p];
        const v4f ub = U[rloc + 2*p + 1];
        xp0[p] = (v2f){ua.x * INV2K, ub.x * INV2K};
        xp1[p] = (v2f){ua.y * INV2K, ub.y * INV2K};
        xp2[p] = (v2f){ua.z * INV2K, ub.z * INV2K};
        acc2[p] = (v2f){0.f, 0.f};
    }
    #pragma unroll 4
    for (int s = 0; s < 16; ++s) {
        const v4f t = T[jb + (s << 6)];
        const float ad = dv[s];
        const v2f a0v = (v2f){t.x, t.x}, a1v = (v2f){t.y, t.y};
        const v2f a2v = (v2f){t.z, t.z}, adv = (v2f){ad, ad};
        #pragma unroll
        for (int qq = 0; qq < 4; ++qq) {
            v2f d = __builtin_elementwise_fma(xp0[qq], a0v,
                    __builtin_elementwise_fma(xp1[qq], a1v,
                    __builtin_elementwise_fma(xp2[qq], a2v, adv)));
            acc2[qq] += (v2f){EXP2F(d.x), EXP2F(d.y)};
        }
    }
    float acc[8];
    #pragma unroll
    for (int p = 0; p < 4; ++p) { acc[2*p] = acc2[p].x; acc[2*p+1] = acc2[p].y; }
    float v1 = bfly8(acc, lane);
    const int rr = ((lane & 1) << 2) | (lane & 2) | ((lane >> 2) & 1);
    if (lane < 8) pcomb[w * 8 + rr] = v1;
    __syncthreads();
    float Sc = 0.f;
    if (lane < 8) Sc = v1 + pcomb[(w ^ 1) * 8 + rr];
    return Sc;
}

__global__ __launch_bounds__(1024, 4) void emd_sinkhornA(
    const float* __restrict__ x, const float* __restrict__ y,
    float* __restrict__ Af, float* __restrict__ Bf,
    int* __restrict__ flags, float* __restrict__ out)
{
    extern __shared__ float S[];     // 128 KB
    __shared__ float pcomb[16 * 8];
    __shared__ float wsum[16];

    const int tid  = threadIdx.x;
    const int lane = tid & 63;
    const int w    = tid >> 6;
    const int pr   = w >> 1;
    const int jh   = w & 1;
    const int blk  = blockIdx.x;
    const int pair = blk & 7;
    const int q    = blk >> 3;
    const int b0   = pair * 2, b1 = b0 + 1;
    const int base0 = b0 * NN, base1 = b1 * NN;
    const int rloc  = q * 64 + pr * 8;
    int* f0 = flags + 4096 + b0 * 128;   // upper half of the 16 KB flag ws
    int* f1 = flags + 4096 + b1 * 128;

    v4f *sy0 = (v4f*)S;
    v4f *sx0 = (v4f*)S + 1*NN;
    v4f *sy1 = (v4f*)S + 2*NN;
    v4f *sx1 = (v4f*)S + 3*NN;

    #pragma unroll
    for (int v = 0; v < 2; ++v) {
        const int p = tid + (v << 10);
        {
            const float* px = x + 3 * (size_t)(base0 + p);
            sx0[p] = (v4f){TWO_K2E * px[0], TWO_K2E * px[1], TWO_K2E * px[2], 0.f};
            const float* py = y + 3 * (size_t)(base0 + p);
            sy0[p] = (v4f){TWO_K2E * py[0], TWO_K2E * py[1], TWO_K2E * py[2], 0.f};
        }
        {
            const float* px = x + 3 * (size_t)(base1 + p);
            sx1[p] = (v4f){TWO_K2E * px[0], TWO_K2E * px[1], TWO_K2E * px[2], 0.f};
            const float* py = y + 3 * (size_t)(base1 + p);
            sy1[p] = (v4f){TWO_K2E * py[0], TWO_K2E * py[1], TWO_K2E * py[2], 0.f};
        }
    }
    if (tid < 128) {
        const int bb  = tid >> 6;
        const int col = q * 64 + (tid & 63);
        const int bs  = bb ? base1 : base0;
        const float* py = y + 3 * (size_t)(bs + col);
        const float a = py[0], b = py[1], c = py[2];
        DSTORE(&Bf[bs + col], -K2E * (a*a + b*b + c*c));
    }
    __syncthreads();
    if (tid == 0) {
        __hip_atomic_store(f0 + q * 4, 1, __ATOMIC_RELEASE, __HIP_MEMORY_SCOPE_AGENT);
        __hip_atomic_store(f1 + q * 4, 1, __ATOMIC_RELEASE, __HIP_MEMORY_SCOPE_AGENT);
    }

    const int rr = ((lane & 1) << 2) | (lane & 2) | ((lane >> 2) & 1);

    #define PW2(pslot, pval, warr, tgt) do { __syncthreads();                   \
        if (tid == 0)                                                           \
            __hip_atomic_store((pslot), (pval), __ATOMIC_RELEASE,               \
                               __HIP_MEMORY_SCOPE_AGENT);                       \
        if (w == 0) {                                                           \
            for (;;) {                                                          \
                int vv = (lane < 32)                                            \
                    ? __hip_atomic_load((warr) + lane * 4, __ATOMIC_RELAXED,    \
                                        __HIP_MEMORY_SCOPE_AGENT)               \
                    : 0x7fffffff;                                               \
                if (__ballot(vv >= (tgt)) == ~0ULL) break;                      \
                __builtin_amdgcn_s_sleep(1);                                    \
            }                                                                   \
        }                                                                       \
        __syncthreads(); } while (0)

    #define WONLY2(warr, tgt) do { __syncthreads();                             \
        if (w == 0) {                                                           \
            for (;;) {                                                          \
                int vv = (lane < 32)                                            \
                    ? __hip_atomic_load((warr) + lane * 4, __ATOMIC_RELAXED,    \
                                        __HIP_MEMORY_SCOPE_AGENT)               \
                    : 0x7fffffff;                                               \
                if (__ballot(vv >= (tgt)) == ~0ULL) break;                      \
                __builtin_amdgcn_s_sleep(1);                                    \
            }                                                                   \
        }                                                                       \
        __syncthreads(); } while (0)

    WONLY2(f0, 1);

    float Aval0 = 0.f, Aval1 = 0.f;

    for (int it = 0; it < NITERS; ++it) {
        {
            float Sc = sumpassA(sx0, sy0, Bf + base0, rloc, jh, lane, w, pcomb);
            Aval0 = LMU - __log2f(Sc);
            if (lane < 8 && jh == 0) DSTORE(&Af[base0 + rloc + rr], Aval0);
        }
        PW2(f0 + q * 4, 2 * it + 2, f1, 2 * it + 1);
        {
            float Sc = sumpassA(sx1, sy1, Bf + base1, rloc, jh, lane, w, pcomb);
            Aval1 = LMU - __log2f(Sc);
            if (lane < 8 && jh == 0) DSTORE(&Af[base1 + rloc + rr], Aval1);
        }
        PW2(f1 + q * 4, 2 * it + 2, f0, 2 * it + 2);
        {
            float Sc = sumpassA(sy0, sx0, Af + base0, rloc, jh, lane, w, pcomb);
            if (lane < 8 && jh == 0)
                DSTORE(&Bf[base0 + rloc + rr], LMU - __log2f(Sc));
        }
        PW2(f0 + q * 4, 2 * it + 3, f1, 2 * it + 2);
        {
            float Sc = sumpassA(sy1, sx1, Af + base1, rloc, jh, lane, w, pcomb);
            if (lane < 8 && jh == 0)
                DSTORE(&Bf[base1 + rloc + rr], LMU - __log2f(Sc));
        }
        PW2(f1 + q * 4, 2 * it + 3, f0, 2 * it + 3);
    }
    WONLY2(f1, 2 * NITERS + 1);

    {
        float s = epilA(sx0, sy0, Bf + base0, Aval0, rloc, jh, lane)
                + epilA(sx1, sy1, Bf + base1, Aval1, rloc, jh, lane);
        #pragma unroll
        for (int m = 32; m > 0; m >>= 1) s += __shfl_xor(s, m, 64);
        if (lane == 0) wsum[w] = s;
        __syncthreads();
        if (tid == 0) {
            float t = 0.f;
            #pragma unroll
            for (int i = 0; i < 16; ++i) t += wsum[i];
            atomicAdd(out, t * (1.0f / (float)BB));
        }
    }
    #undef PW2
    #undef WONLY2
}

extern "C" void kernel_launch(void* const* d_in, const int* in_sizes, int n_in,
                              void* d_out, int out_size, void* d_ws, size_t ws_size,
                              hipStream_t stream) {
    const float* x = (const float*)d_in[0];
    const float* y = (const float*)d_in[1];
    float* out = (float*)d_out;
    char* ws = (char*)d_ws;

    int*   flags = (int*)ws;                                 // 16 KB (Z: lower 4 KB; A: upper 8 KB)
    float* Af    = (float*)(ws + 16384);                     // 128 KB
    float* Bf    = (float*)(ws + 16384 + (size_t)BB*NN*sizeof(float));

    hipMemsetAsync(flags, 0, 16384, stream);
    hipMemsetAsync(out, 0, sizeof(float), stream);

    void* args[] = {(void*)&x, (void*)&y, (void*)&Af, (void*)&Bf,
                    (void*)&flags, (void*)&out};

    const size_t shmem = (size_t)4 * NN * 4 * sizeof(float);    // 128 KB
    hipError_t ez = hipFuncSetAttribute((const void*)emd_sinkhornZ,
                        hipFuncAttributeMaxDynamicSharedMemorySize, (int)shmem);
    hipError_t e = (ez == hipSuccess)
        ? hipLaunchCooperativeKernel((const void*)emd_sinkhornZ,
                                     dim3(256), dim3(1024), args, shmem, stream)
        : hipErrorInvalidValue;
    if (e != hipSuccess) {
        // Fallback: verified R18 AoS kernel (2960 us)
        hipError_t ea = hipFuncSetAttribute((const void*)emd_sinkhornA,
                            hipFuncAttributeMaxDynamicSharedMemorySize, (int)shmem);
        hipError_t e2 = (ea == hipSuccess)
            ? hipLaunchCooperativeKernel((const void*)emd_sinkhornA,
                                         dim3(256), dim3(1024), args, shmem, stream)
            : hipErrorInvalidValue;
        if (e2 != hipSuccess) {
            hipLaunchKernelGGL(emd_sinkhornA, dim3(256), dim3(1024), shmem,
                               stream, x, y, Af, Bf, flags, out);
        }
    }
}

// Round 9
// 2812.125 us; speedup vs baseline: 1.7158x; 1.7158x over previous
//
#include <hip/hip_runtime.h>

#define BB 16
#define NN 2048
#define NITERS 100

// k = log2(e)/eps, eps = 0.05
#define K2E      28.853900817779268f
#define TWO_K2E  57.707801635558536f
#define INV2K    0.017328679513998632f   // 1/(2k)
#define INV_K2E  0.034657359027997264f
#define INV4K    0.008664339756999316f   // 1/(4k)
#define LMU      (-11.0f)                // log2(1/2048)

#if __has_builtin(__builtin_amdgcn_exp2f)
#define EXP2F(x) __builtin_amdgcn_exp2f(x)
#else
#define EXP2F(x) exp2f(x)
#endif

typedef float v2f __attribute__((ext_vector_type(2)));
typedef float v4f __attribute__((ext_vector_type(4)));

// device-coherent (LLC-homed) accessors for the dual arrays
#define DSTORE(p, v) __hip_atomic_store((p), (v), __ATOMIC_RELAXED, __HIP_MEMORY_SCOPE_AGENT)
#define DLOAD(p)     __hip_atomic_load((p), __ATOMIC_RELAXED, __HIP_MEMORY_SCOPE_AGENT)

// verified multi-value butterfly: 8 partials -> full row-sum on lanes 0..7
// at row index rr = ((lane&1)<<2)|(lane&2)|((lane>>2)&1)
__device__ __forceinline__ float bfly8(const float acc[8], int lane) {
    const bool b0 = lane & 1, b1 = lane & 2, b2 = lane & 4;
    float v4[4], v2_[2], v1;
    #pragma unroll
    for (int i = 0; i < 4; ++i) {
        float recv = __shfl_xor(b0 ? acc[i] : acc[i+4], 1, 64);
        v4[i] = (b0 ? acc[i+4] : acc[i]) + recv;
    }
    #pragma unroll
    for (int i = 0; i < 2; ++i) {
        float recv = __shfl_xor(b1 ? v4[i] : v4[i+2], 2, 64);
        v2_[i] = (b1 ? v4[i+2] : v4[i]) + recv;
    }
    {
        float recv = __shfl_xor(b2 ? v2_[0] : v2_[1], 4, 64);
        v1 = (b2 ? v2_[1] : v2_[0]) + recv;
    }
    v1 += __shfl_xor(v1, 8, 64);
    v1 += __shfl_xor(v1, 16, 64);
    v1 += __shfl_xor(v1, 32, 64);
    return v1;
}

// R7-verified AoS sum-pass (2960 us kernel): 8 rows/wave, own j-half,
// ds_read_b128 tables, 16 LLC dual preloads, unroll 4. UNCHANGED.
__device__ __forceinline__ float sumpassA(
    const v4f* __restrict__ U, const v4f* __restrict__ T,
    const float* __restrict__ gd,
    int rloc, int jh, int lane, int w, float* pcomb)
{
    const int jb = (jh << 10) + lane;
    float dv[16];
    #pragma unroll
    for (int s = 0; s < 16; ++s)
        dv[s] = DLOAD(gd + jb + (s << 6));

    v2f xp0[4], xp1[4], xp2[4], acc2[4];
    #pragma unroll
    for (int p = 0; p < 4; ++p) {
        const v4f ua = U[rloc + 2*p];
        const v4f ub = U[rloc + 2*p + 1];
        xp0[p] = (v2f){ua.x * INV2K, ub.x * INV2K};
        xp1[p] = (v2f){ua.y * INV2K, ub.y * INV2K};
        xp2[p] = (v2f){ua.z * INV2K, ub.z * INV2K};
        acc2[p] = (v2f){0.f, 0.f};
    }
    #pragma unroll 4
    for (int s = 0; s < 16; ++s) {
        const v4f t = T[jb + (s << 6)];
        const float ad = dv[s];
        const v2f a0v = (v2f){t.x, t.x}, a1v = (v2f){t.y, t.y};
        const v2f a2v = (v2f){t.z, t.z}, adv = (v2f){ad, ad};
        #pragma unroll
        for (int qq = 0; qq < 4; ++qq) {
            v2f d = __builtin_elementwise_fma(xp0[qq], a0v,
                    __builtin_elementwise_fma(xp1[qq], a1v,
                    __builtin_elementwise_fma(xp2[qq], a2v, adv)));
            acc2[qq] += (v2f){EXP2F(d.x), EXP2F(d.y)};
        }
    }
    float acc[8];
    #pragma unroll
    for (int p = 0; p < 4; ++p) { acc[2*p] = acc2[p].x; acc[2*p+1] = acc2[p].y; }
    float v1 = bfly8(acc, lane);
    const int rr = ((lane & 1) << 2) | (lane & 2) | ((lane >> 2) & 1);
    if (lane < 8) pcomb[w * 8 + rr] = v1;
    __syncthreads();
    float Sc = 0.f;
    if (lane < 8) Sc = v1 + pcomb[(w ^ 1) * 8 + rr];
    return Sc;
}

// Epilogue partial: sum_j P_ij*C_ij, 8 rows x own j-half; AoS tables.
// (R7-verified — runs once, ~1% of runtime)
__device__ __forceinline__ float epilA(
    const v4f* __restrict__ U, const v4f* __restrict__ T,
    const float* __restrict__ gB,
    float Aval, int rloc, int jh, int lane)
{
    const int jb = (jh << 10) + lane;
    float dv[16];
    #pragma unroll
    for (int s = 0; s < 16; ++s)
        dv[s] = DLOAD(gB + jb + (s << 6));

    float xr0[8], xr1[8], xr2[8], Ak[8], x2k[8];
    #pragma unroll
    for (int k = 0; k < 8; ++k) {
        const v4f u = U[rloc + k];
        xr0[k] = u.x * INV2K;
        xr1[k] = u.y * INV2K;
        xr2[k] = u.z * INV2K;
        const int src = ((k & 1) << 2) | (k & 2) | ((k >> 2) & 1);
        Ak[k]  = __shfl(Aval, src, 64);
        x2k[k] = K2E * (xr0[k]*xr0[k] + xr1[k]*xr1[k] + xr2[k]*xr2[k]);
    }
    float acc = 0.f;
    for (int s = 0; s < 16; ++s) {
        const v4f t = T[jb + (s << 6)];
        const float a0 = t.x, a1 = t.y, a2 = t.z, tb = dv[s];
        const float q2 = (a0*a0 + a1*a1 + a2*a2) * INV4K;   // k|y|^2
        #pragma unroll
        for (int k = 0; k < 8; ++k) {
            float d = fmaf(xr0[k], a0, fmaf(xr1[k], a1, fmaf(xr2[k], a2, tb)));
            float P = EXP2F(d + Ak[k]);                       // exp(logP)
            float C = fmaxf((x2k[k] + q2 - (d - tb)) * INV_K2E, 0.f);
            acc = fmaf(P, C, acc);
        }
    }
    return acc;
}

// R20: SEQUENTIAL-FUSED 2-phase schedule. Identical pass bodies to the
// verified R18/R7 kernel (no register-pressure change — this isolates the
// sync-count variable that R8's spill confounded). Per iteration:
//   {fA0; fA1} -> PW -> {gB0; gB1} -> PW
// fA0/fA1 are independent (both consume the completed Bf), so one post+wait
// pair per half-iteration suffices: 200 sync events instead of 400.
// Trade: waits are zero-slack. This round measures which effect dominates.
__global__ __launch_bounds__(1024, 4) void emd_sinkhornS(
    const float* __restrict__ x, const float* __restrict__ y,
    float* __restrict__ Af, float* __restrict__ Bf,
    int* __restrict__ flags, float* __restrict__ out)
{
    extern __shared__ float S[];     // 4 * NN * 4 floats = 128 KB
    __shared__ float pcomb[16 * 8];
    __shared__ float wsum[16];

    const int tid  = threadIdx.x;
    const int lane = tid & 63;
    const int w    = tid >> 6;        // 0..15
    const int pr   = w >> 1;          // wave-pair 0..7
    const int jh   = w & 1;           // j-half
    const int blk  = blockIdx.x;
    const int pair = blk & 7;         // = XCD id under round-robin (perf only)
    const int q    = blk >> 3;        // 0..31: row-slice within pair
    const int b0   = pair * 2, b1 = b0 + 1;
    const int base0 = b0 * NN, base1 = b1 * NN;
    const int rloc  = q * 64 + pr * 8;      // within-batch row base
    int* fp = flags + pair * 128;     // ONE array per pair: 32 slots x 16 B

    v4f *sy0 = (v4f*)S;               // batch0 y (2k-scaled, AoS)
    v4f *sx0 = (v4f*)S + 1*NN;        // batch0 x
    v4f *sy1 = (v4f*)S + 2*NN;        // batch1 y
    v4f *sx1 = (v4f*)S + 3*NN;        // batch1 x

    // ---- prologue: stage 2k-scaled AoS tables ----
    #pragma unroll
    for (int v = 0; v < 2; ++v) {
        const int p = tid + (v << 10);
        {
            const float* px = x + 3 * (size_t)(base0 + p);
            sx0[p] = (v4f){TWO_K2E * px[0], TWO_K2E * px[1], TWO_K2E * px[2], 0.f};
            const float* py = y + 3 * (size_t)(base0 + p);
            sy0[p] = (v4f){TWO_K2E * py[0], TWO_K2E * py[1], TWO_K2E * py[2], 0.f};
        }
        {
            const float* px = x + 3 * (size_t)(base1 + p);
            sx1[p] = (v4f){TWO_K2E * px[0], TWO_K2E * px[1], TWO_K2E * px[2], 0.f};
            const float* py = y + 3 * (size_t)(base1 + p);
            sy1[p] = (v4f){TWO_K2E * py[0], TWO_K2E * py[1], TWO_K2E * py[2], 0.f};
        }
    }
    // ---- prologue: B0-init for own 64 columns of both batches ----
    if (tid < 128) {
        const int bb  = tid >> 6;
        const int col = q * 64 + (tid & 63);
        const int bs  = bb ? base1 : base0;
        const float* py = y + 3 * (size_t)(bs + col);
        const float a = py[0], b = py[1], c = py[2];
        DSTORE(&Bf[bs + col], -K2E * (a*a + b*b + c*c));
    }
    __syncthreads();                  // drains table + B-init stores
    if (tid == 0)
        __hip_atomic_store(fp + q * 4, 1, __ATOMIC_RELEASE, __HIP_MEMORY_SCOPE_AGENT);

    // post own phase into own slot + wait all 32 slots (same array)
    #define PW(pval, tgt) do { __syncthreads();                                 \
        if (tid == 0)                                                           \
            __hip_atomic_store(fp + q * 4, (pval), __ATOMIC_RELEASE,            \
                               __HIP_MEMORY_SCOPE_AGENT);                       \
        if (w == 0) {                                                           \
            for (;;) {                                                          \
                int vv = (lane < 32)                                            \
                    ? __hip_atomic_load(fp + lane * 4, __ATOMIC_RELAXED,        \
                                        __HIP_MEMORY_SCOPE_AGENT)               \
                    : 0x7fffffff;                                               \
                if (__ballot(vv >= (tgt)) == ~0ULL) break;                      \
                __builtin_amdgcn_s_sleep(1);                                    \
            }                                                                   \
        }                                                                       \
        __syncthreads(); } while (0)

    PW(1, 1);                         // all B-inits of the pair visible

    const int rr = ((lane & 1) << 2) | (lane & 2) | ((lane >> 2) & 1);
    float Aval0 = 0.f, Aval1 = 0.f;

    for (int it = 0; it < NITERS; ++it) {
        // ---- f half-iteration: fA0 then fA1 (both consume completed Bf) ----
        {
            float Sc = sumpassA(sx0, sy0, Bf + base0, rloc, jh, lane, w, pcomb);
            Aval0 = LMU - __log2f(Sc);
            if (lane < 8 && jh == 0) DSTORE(&Af[base0 + rloc + rr], Aval0);
        }
        {
            float Sc = sumpassA(sx1, sy1, Bf + base1, rloc, jh, lane, w, pcomb);
            Aval1 = LMU - __log2f(Sc);
            if (lane < 8 && jh == 0) DSTORE(&Af[base1 + rloc + rr], Aval1);
        }
        PW(2 * it + 2, 2 * it + 2);   // post f; wait all peers' f
        // ---- g half-iteration: gB0 then gB1 (both consume completed Af) ----
        {
            float Sc = sumpassA(sy0, sx0, Af + base0, rloc, jh, lane, w, pcomb);
            if (lane < 8 && jh == 0)
                DSTORE(&Bf[base0 + rloc + rr], LMU - __log2f(Sc));
        }
        {
            float Sc = sumpassA(sy1, sx1, Af + base1, rloc, jh, lane, w, pcomb);
            if (lane < 8 && jh == 0)
                DSTORE(&Bf[base1 + rloc + rr], LMU - __log2f(Sc));
        }
        PW(2 * it + 3, 2 * it + 3);   // post g; wait all peers' g
    }
    // last PW (201) guarantees final Bf of both batches complete

    // ---- epilogue: own 64 rows of each batch, own j-half ----
    {
        float s = epilA(sx0, sy0, Bf + base0, Aval0, rloc, jh, lane)
                + epilA(sx1, sy1, Bf + base1, Aval1, rloc, jh, lane);
        #pragma unroll
        for (int m = 32; m > 0; m >>= 1) s += __shfl_xor(s, m, 64);
        if (lane == 0) wsum[w] = s;
        __syncthreads();
        if (tid == 0) {
            float t = 0.f;
            #pragma unroll
            for (int i = 0; i < 16; ++i) t += wsum[i];
            atomicAdd(out, t * (1.0f / (float)BB));
        }
    }
    #undef PW
}

// =============== verified R18/R7 AoS kernel (launch fallback) ===============
__global__ __launch_bounds__(1024, 4) void emd_sinkhornA(
    const float* __restrict__ x, const float* __restrict__ y,
    float* __restrict__ Af, float* __restrict__ Bf,
    int* __restrict__ flags, float* __restrict__ out)
{
    extern __shared__ float S[];     // 128 KB
    __shared__ float pcomb[16 * 8];
    __shared__ float wsum[16];

    const int tid  = threadIdx.x;
    const int lane = tid & 63;
    const int w    = tid >> 6;
    const int pr   = w >> 1;
    const int jh   = w & 1;
    const int blk  = blockIdx.x;
    const int pair = blk & 7;
    const int q    = blk >> 3;
    const int b0   = pair * 2, b1 = b0 + 1;
    const int base0 = b0 * NN, base1 = b1 * NN;
    const int rloc  = q * 64 + pr * 8;
    int* f0 = flags + 4096 + b0 * 128;   // upper region of the 16 KB flag ws
    int* f1 = flags + 4096 + b1 * 128;

    v4f *sy0 = (v4f*)S;
    v4f *sx0 = (v4f*)S + 1*NN;
    v4f *sy1 = (v4f*)S + 2*NN;
    v4f *sx1 = (v4f*)S + 3*NN;

    #pragma unroll
    for (int v = 0; v < 2; ++v) {
        const int p = tid + (v << 10);
        {
            const float* px = x + 3 * (size_t)(base0 + p);
            sx0[p] = (v4f){TWO_K2E * px[0], TWO_K2E * px[1], TWO_K2E * px[2], 0.f};
            const float* py = y + 3 * (size_t)(base0 + p);
            sy0[p] = (v4f){TWO_K2E * py[0], TWO_K2E * py[1], TWO_K2E * py[2], 0.f};
        }
        {
            const float* px = x + 3 * (size_t)(base1 + p);
            sx1[p] = (v4f){TWO_K2E * px[0], TWO_K2E * px[1], TWO_K2E * px[2], 0.f};
            const float* py = y + 3 * (size_t)(base1 + p);
            sy1[p] = (v4f){TWO_K2E * py[0], TWO_K2E * py[1], TWO_K2E * py[2], 0.f};
        }
    }
    if (tid < 128) {
        const int bb  = tid >> 6;
        const int col = q * 64 + (tid & 63);
        const int bs  = bb ? base1 : base0;
        const float* py = y + 3 * (size_t)(bs + col);
        const float a = py[0], b = py[1], c = py[2];
        DSTORE(&Bf[bs + col], -K2E * (a*a + b*b + c*c));
    }
    __syncthreads();
    if (tid == 0) {
        __hip_atomic_store(f0 + q * 4, 1, __ATOMIC_RELEASE, __HIP_MEMORY_SCOPE_AGENT);
        __hip_atomic_store(f1 + q * 4, 1, __ATOMIC_RELEASE, __HIP_MEMORY_SCOPE_AGENT);
    }

    const int rr = ((lane & 1) << 2) | (lane & 2) | ((lane >> 2) & 1);

    #define PW2(pslot, pval, warr, tgt) do { __syncthreads();                   \
        if (tid == 0)                                                           \
            __hip_atomic_store((pslot), (pval), __ATOMIC_RELEASE,               \
                               __HIP_MEMORY_SCOPE_AGENT);                       \
        if (w == 0) {                                                           \
            for (;;) {                                                          \
                int vv = (lane < 32)                                            \
                    ? __hip_atomic_load((warr) + lane * 4, __ATOMIC_RELAXED,    \
                                        __HIP_MEMORY_SCOPE_AGENT)               \
                    : 0x7fffffff;                                               \
                if (__ballot(vv >= (tgt)) == ~0ULL) break;                      \
                __builtin_amdgcn_s_sleep(1);                                    \
            }                                                                   \
        }                                                                       \
        __syncthreads(); } while (0)

    #define WONLY2(warr, tgt) do { __syncthreads();                             \
        if (w == 0) {                                                           \
            for (;;) {                                                          \
                int vv = (lane < 32)                                            \
                    ? __hip_atomic_load((warr) + lane * 4, __ATOMIC_RELAXED,    \
                                        __HIP_MEMORY_SCOPE_AGENT)               \
                    : 0x7fffffff;                                               \
                if (__ballot(vv >= (tgt)) == ~0ULL) break;                      \
                __builtin_amdgcn_s_sleep(1);                                    \
            }                                                                   \
        }                                                                       \
        __syncthreads(); } while (0)

    WONLY2(f0, 1);

    float Aval0 = 0.f, Aval1 = 0.f;

    for (int it = 0; it < NITERS; ++it) {
        {
            float Sc = sumpassA(sx0, sy0, Bf + base0, rloc, jh, lane, w, pcomb);
            Aval0 = LMU - __log2f(Sc);
            if (lane < 8 && jh == 0) DSTORE(&Af[base0 + rloc + rr], Aval0);
        }
        PW2(f0 + q * 4, 2 * it + 2, f1, 2 * it + 1);
        {
            float Sc = sumpassA(sx1, sy1, Bf + base1, rloc, jh, lane, w, pcomb);
            Aval1 = LMU - __log2f(Sc);
            if (lane < 8 && jh == 0) DSTORE(&Af[base1 + rloc + rr], Aval1);
        }
        PW2(f1 + q * 4, 2 * it + 2, f0, 2 * it + 2);
        {
            float Sc = sumpassA(sy0, sx0, Af + base0, rloc, jh, lane, w, pcomb);
            if (lane < 8 && jh == 0)
                DSTORE(&Bf[base0 + rloc + rr], LMU - __log2f(Sc));
        }
        PW2(f0 + q * 4, 2 * it + 3, f1, 2 * it + 2);
        {
            float Sc = sumpassA(sy1, sx1, Af + base1, rloc, jh, lane, w, pcomb);
            if (lane < 8 && jh == 0)
                DSTORE(&Bf[base1 + rloc + rr], LMU - __log2f(Sc));
        }
        PW2(f1 + q * 4, 2 * it + 3, f0, 2 * it + 3);
    }
    WONLY2(f1, 2 * NITERS + 1);

    {
        float s = epilA(sx0, sy0, Bf + base0, Aval0, rloc, jh, lane)
                + epilA(sx1, sy1, Bf + base1, Aval1, rloc, jh, lane);
        #pragma unroll
        for (int m = 32; m > 0; m >>= 1) s += __shfl_xor(s, m, 64);
        if (lane == 0) wsum[w] = s;
        __syncthreads();
        if (tid == 0) {
            float t = 0.f;
            #pragma unroll
            for (int i = 0; i < 16; ++i) t += wsum[i];
            atomicAdd(out, t * (1.0f / (float)BB));
        }
    }
    #undef PW2
    #undef WONLY2
}

extern "C" void kernel_launch(void* const* d_in, const int* in_sizes, int n_in,
                              void* d_out, int out_size, void* d_ws, size_t ws_size,
                              hipStream_t stream) {
    const float* x = (const float*)d_in[0];
    const float* y = (const float*)d_in[1];
    float* out = (float*)d_out;
    char* ws = (char*)d_ws;

    int*   flags = (int*)ws;                                 // 16 KB (S: lower 4 KB; A: upper)
    float* Af    = (float*)(ws + 16384);                     // 128 KB
    float* Bf    = (float*)(ws + 16384 + (size_t)BB*NN*sizeof(float));

    hipMemsetAsync(flags, 0, 16384, stream);
    hipMemsetAsync(out, 0, sizeof(float), stream);

    void* args[] = {(void*)&x, (void*)&y, (void*)&Af, (void*)&Bf,
                    (void*)&flags, (void*)&out};

    const size_t shmem = (size_t)4 * NN * 4 * sizeof(float);    // 128 KB
    hipError_t es = hipFuncSetAttribute((const void*)emd_sinkhornS,
                        hipFuncAttributeMaxDynamicSharedMemorySize, (int)shmem);
    hipError_t e = (es == hipSuccess)
        ? hipLaunchCooperativeKernel((const void*)emd_sinkhornS,
                                     dim3(256), dim3(1024), args, shmem, stream)
        : hipErrorInvalidValue;
    if (e != hipSuccess) {
        // Fallback: verified R18/R7 AoS kernel (2960 us)
        hipError_t ea = hipFuncSetAttribute((const void*)emd_sinkhornA,
                            hipFuncAttributeMaxDynamicSharedMemorySize, (int)shmem);
        hipError_t e2 = (ea == hipSuccess)
            ? hipLaunchCooperativeKernel((const void*)emd_sinkhornA,
                                         dim3(256), dim3(1024), args, shmem, stream)
            : hipErrorInvalidValue;
        if (e2 != hipSuccess) {
            hipLaunchKernelGGL(emd_sinkhornA, dim3(256), dim3(1024), shmem,
                               stream, x, y, Af, Bf, flags, out);
        }
    }
}

// Round 10
// 2493.605 us; speedup vs baseline: 1.9350x; 1.1277x over previous
//
#include <hip/hip_runtime.h>

#define BB 16
#define NN 2048
#define NITERS 100

// k = log2(e)/eps, eps = 0.05
#define K2E      28.853900817779268f
#define TWO_K2E  57.707801635558536f
#define INV2K    0.017328679513998632f   // 1/(2k)
#define INV_K2E  0.034657359027997264f
#define INV4K    0.008664339756999316f   // 1/(4k)
#define LMU      (-11.0f)                // log2(1/2048)

#if __has_builtin(__builtin_amdgcn_exp2f)
#define EXP2F(x) __builtin_amdgcn_exp2f(x)
#else
#define EXP2F(x) exp2f(x)
#endif

typedef float v2f __attribute__((ext_vector_type(2)));
typedef float v4f __attribute__((ext_vector_type(4)));

// device-coherent (LLC-homed) accessors for the dual arrays
#define DSTORE(p, v) __hip_atomic_store((p), (v), __ATOMIC_RELAXED, __HIP_MEMORY_SCOPE_AGENT)
#define DLOAD(p)     __hip_atomic_load((p), __ATOMIC_RELAXED, __HIP_MEMORY_SCOPE_AGENT)

// verified multi-value butterfly: 8 partials -> full row-sum on lanes 0..7
// at row index rr = ((lane&1)<<2)|(lane&2)|((lane>>2)&1)
__device__ __forceinline__ float bfly8(const float acc[8], int lane) {
    const bool b0 = lane & 1, b1 = lane & 2, b2 = lane & 4;
    float v4[4], v2_[2], v1;
    #pragma unroll
    for (int i = 0; i < 4; ++i) {
        float recv = __shfl_xor(b0 ? acc[i] : acc[i+4], 1, 64);
        v4[i] = (b0 ? acc[i+4] : acc[i]) + recv;
    }
    #pragma unroll
    for (int i = 0; i < 2; ++i) {
        float recv = __shfl_xor(b1 ? v4[i] : v4[i+2], 2, 64);
        v2_[i] = (b1 ? v4[i+2] : v4[i]) + recv;
    }
    {
        float recv = __shfl_xor(b2 ? v2_[0] : v2_[1], 4, 64);
        v1 = (b2 ? v2_[1] : v2_[0]) + recv;
    }
    v1 += __shfl_xor(v1, 8, 64);
    v1 += __shfl_xor(v1, 16, 64);
    v1 += __shfl_xor(v1, 32, 64);
    return v1;
}

// R21 sum-pass with LDS-STAGED DUALS: identical math/structure to the
// verified R7/R9 pass body, but dv comes from the per-phase staged LDS
// buffer (ds_read ~120cy) instead of 16 direct LLC loads (~600-900cy).
// Register pressure unchanged (dv[16] + 12 coord + 8 acc).
__device__ __forceinline__ float sumpassL(
    const v4f* __restrict__ U, const v4f* __restrict__ T,
    const float* __restrict__ sdv,   // LDS dual buffer, linear [0..NN)
    int rloc, int jh, int lane, int w, float* pcomb)
{
    const int jb = (jh << 10) + lane;
    float dv[16];
    #pragma unroll
    for (int s = 0; s < 16; ++s)
        dv[s] = sdv[jb + (s << 6)];

    v2f xp0[4], xp1[4], xp2[4], acc2[4];
    #pragma unroll
    for (int p = 0; p < 4; ++p) {
        const v4f ua = U[rloc + 2*p];
        const v4f ub = U[rloc + 2*p + 1];
        xp0[p] = (v2f){ua.x * INV2K, ub.x * INV2K};
        xp1[p] = (v2f){ua.y * INV2K, ub.y * INV2K};
        xp2[p] = (v2f){ua.z * INV2K, ub.z * INV2K};
        acc2[p] = (v2f){0.f, 0.f};
    }
    #pragma unroll 4
    for (int s = 0; s < 16; ++s) {
        const v4f t = T[jb + (s << 6)];
        const float ad = dv[s];
        const v2f a0v = (v2f){t.x, t.x}, a1v = (v2f){t.y, t.y};
        const v2f a2v = (v2f){t.z, t.z}, adv = (v2f){ad, ad};
        #pragma unroll
        for (int qq = 0; qq < 4; ++qq) {
            v2f d = __builtin_elementwise_fma(xp0[qq], a0v,
                    __builtin_elementwise_fma(xp1[qq], a1v,
                    __builtin_elementwise_fma(xp2[qq], a2v, adv)));
            acc2[qq] += (v2f){EXP2F(d.x), EXP2F(d.y)};
        }
    }
    float acc[8];
    #pragma unroll
    for (int p = 0; p < 4; ++p) { acc[2*p] = acc2[p].x; acc[2*p+1] = acc2[p].y; }
    float v1 = bfly8(acc, lane);
    const int rr = ((lane & 1) << 2) | (lane & 2) | ((lane >> 2) & 1);
    if (lane < 8) pcomb[w * 8 + rr] = v1;
    __syncthreads();
    float Sc = 0.f;
    if (lane < 8) Sc = v1 + pcomb[(w ^ 1) * 8 + rr];
    return Sc;
}

// R7-verified AoS sum-pass with direct LLC duals (fallback kernel only).
__device__ __forceinline__ float sumpassA(
    const v4f* __restrict__ U, const v4f* __restrict__ T,
    const float* __restrict__ gd,
    int rloc, int jh, int lane, int w, float* pcomb)
{
    const int jb = (jh << 10) + lane;
    float dv[16];
    #pragma unroll
    for (int s = 0; s < 16; ++s)
        dv[s] = DLOAD(gd + jb + (s << 6));

    v2f xp0[4], xp1[4], xp2[4], acc2[4];
    #pragma unroll
    for (int p = 0; p < 4; ++p) {
        const v4f ua = U[rloc + 2*p];
        const v4f ub = U[rloc + 2*p + 1];
        xp0[p] = (v2f){ua.x * INV2K, ub.x * INV2K};
        xp1[p] = (v2f){ua.y * INV2K, ub.y * INV2K};
        xp2[p] = (v2f){ua.z * INV2K, ub.z * INV2K};
        acc2[p] = (v2f){0.f, 0.f};
    }
    #pragma unroll 4
    for (int s = 0; s < 16; ++s) {
        const v4f t = T[jb + (s << 6)];
        const float ad = dv[s];
        const v2f a0v = (v2f){t.x, t.x}, a1v = (v2f){t.y, t.y};
        const v2f a2v = (v2f){t.z, t.z}, adv = (v2f){ad, ad};
        #pragma unroll
        for (int qq = 0; qq < 4; ++qq) {
            v2f d = __builtin_elementwise_fma(xp0[qq], a0v,
                    __builtin_elementwise_fma(xp1[qq], a1v,
                    __builtin_elementwise_fma(xp2[qq], a2v, adv)));
            acc2[qq] += (v2f){EXP2F(d.x), EXP2F(d.y)};
        }
    }
    float acc[8];
    #pragma unroll
    for (int p = 0; p < 4; ++p) { acc[2*p] = acc2[p].x; acc[2*p+1] = acc2[p].y; }
    float v1 = bfly8(acc, lane);
    const int rr = ((lane & 1) << 2) | (lane & 2) | ((lane >> 2) & 1);
    if (lane < 8) pcomb[w * 8 + rr] = v1;
    __syncthreads();
    float Sc = 0.f;
    if (lane < 8) Sc = v1 + pcomb[(w ^ 1) * 8 + rr];
    return Sc;
}

// Epilogue partial: sum_j P_ij*C_ij, 8 rows x own j-half; AoS tables.
// (verified — runs once, ~1% of runtime)
__device__ __forceinline__ float epilA(
    const v4f* __restrict__ U, const v4f* __restrict__ T,
    const float* __restrict__ gB,
    float Aval, int rloc, int jh, int lane)
{
    const int jb = (jh << 10) + lane;
    float dv[16];
    #pragma unroll
    for (int s = 0; s < 16; ++s)
        dv[s] = DLOAD(gB + jb + (s << 6));

    float xr0[8], xr1[8], xr2[8], Ak[8], x2k[8];
    #pragma unroll
    for (int k = 0; k < 8; ++k) {
        const v4f u = U[rloc + k];
        xr0[k] = u.x * INV2K;
        xr1[k] = u.y * INV2K;
        xr2[k] = u.z * INV2K;
        const int src = ((k & 1) << 2) | (k & 2) | ((k >> 2) & 1);
        Ak[k]  = __shfl(Aval, src, 64);
        x2k[k] = K2E * (xr0[k]*xr0[k] + xr1[k]*xr1[k] + xr2[k]*xr2[k]);
    }
    float acc = 0.f;
    for (int s = 0; s < 16; ++s) {
        const v4f t = T[jb + (s << 6)];
        const float a0 = t.x, a1 = t.y, a2 = t.z, tb = dv[s];
        const float q2 = (a0*a0 + a1*a1 + a2*a2) * INV4K;   // k|y|^2
        #pragma unroll
        for (int k = 0; k < 8; ++k) {
            float d = fmaf(xr0[k], a0, fmaf(xr1[k], a1, fmaf(xr2[k], a2, tb)));
            float P = EXP2F(d + Ak[k]);                       // exp(logP)
            float C = fmaxf((x2k[k] + q2 - (d - tb)) * INV_K2E, 0.f);
            acc = fmaf(P, C, acc);
        }
    }
    return acc;
}

// R21: one batch per block, 16-block sync groups, LDS-staged duals.
// 256 blocks x 1024 threads (1/CU). batch b = blk>>4, row-slab q = blk&15
// (128 rows). Per iteration (2 sync events, the R9-proven optimum):
//   wait -> stage Bf duals to LDS -> f passes (2 x 64 rows) -> post
//   wait -> stage Af duals to LDS -> g passes -> post
// Group size 16 (was 32): smaller straggler max at each zero-slack wait.
__global__ __launch_bounds__(1024, 4) void emd_sinkhornT(
    const float* __restrict__ x, const float* __restrict__ y,
    float* __restrict__ Af, float* __restrict__ Bf,
    int* __restrict__ flags, float* __restrict__ out)
{
    extern __shared__ float S[];     // sy(32KB) | sx(32KB) | sd(8KB) = 72 KB
    __shared__ float pcomb[16 * 8];
    __shared__ float wsum[16];

    const int tid  = threadIdx.x;
    const int lane = tid & 63;
    const int w    = tid >> 6;        // 0..15
    const int pr   = w >> 1;          // wave-pair 0..7
    const int jh   = w & 1;           // j-half
    const int blk  = blockIdx.x;
    const int b    = blk >> 4;        // batch 0..15
    const int q    = blk & 15;        // row-slab within batch (128 rows)
    const int base = b * NN;
    const int row0 = q * 128;
    const int rlocA = row0 + pr * 8;        // first 64-row call
    const int rlocB = row0 + 64 + pr * 8;   // second 64-row call
    int* fb = flags + b * 64;         // 16 slots x 16 B per batch

    v4f   *sy = (v4f*)S;              // batch y (2k-scaled, AoS)
    v4f   *sx = (v4f*)S + NN;         // batch x
    float *sd = (float*)((v4f*)S + 2 * NN);   // staged duals [NN]

    // ---- prologue: stage 2k-scaled AoS tables for own batch ----
    #pragma unroll
    for (int v = 0; v < 2; ++v) {
        const int p = tid + (v << 10);
        const float* px = x + 3 * (size_t)(base + p);
        sx[p] = (v4f){TWO_K2E * px[0], TWO_K2E * px[1], TWO_K2E * px[2], 0.f};
        const float* py = y + 3 * (size_t)(base + p);
        sy[p] = (v4f){TWO_K2E * py[0], TWO_K2E * py[1], TWO_K2E * py[2], 0.f};
    }
    // ---- prologue: B0-init for own 128 columns ----
    if (tid < 128) {
        const int col = row0 + tid;
        const float* py = y + 3 * (size_t)(base + col);
        const float a = py[0], bb = py[1], c = py[2];
        DSTORE(&Bf[base + col], -K2E * (a*a + bb*bb + c*c));
    }
    __syncthreads();                  // drains table + B-init stores
    if (tid == 0)
        __hip_atomic_store(fb + q * 4, 1, __ATOMIC_RELEASE, __HIP_MEMORY_SCOPE_AGENT);

    // wait: all 16 blocks of own batch posted >= tgt (wave 0 polls)
    #define WAITB(tgt) do { __syncthreads();                                    \
        if (w == 0) {                                                           \
            for (;;) {                                                          \
                int vv = (lane < 16)                                            \
                    ? __hip_atomic_load(fb + lane * 4, __ATOMIC_RELAXED,        \
                                        __HIP_MEMORY_SCOPE_AGENT)               \
                    : 0x7fffffff;                                               \
                if (__ballot(vv >= (tgt)) == ~0ULL) break;                      \
                __builtin_amdgcn_s_sleep(1);                                    \
            }                                                                   \
        }                                                                       \
        __syncthreads(); } while (0)

    // post: entry barrier drains DSTOREs (compiler emits vmcnt(0) before
    // s_barrier), then tid0 release-stores the phase value.
    #define POSTB(pval) do { __syncthreads();                                   \
        if (tid == 0)                                                           \
            __hip_atomic_store(fb + q * 4, (pval), __ATOMIC_RELEASE,            \
                               __HIP_MEMORY_SCOPE_AGENT);                       \
    } while (0)

    // stage one dual array (LLC, coherent DLOAD) into sd[0..NN)
    #define STAGE(gsrc) do {                                                    \
        float t0_ = DLOAD((gsrc) + tid);                                        \
        float t1_ = DLOAD((gsrc) + tid + 1024);                                 \
        sd[tid] = t0_; sd[tid + 1024] = t1_;                                    \
        __syncthreads(); } while (0)

    WAITB(1);                         // all B-inits of the batch visible

    const int rr = ((lane & 1) << 2) | (lane & 2) | ((lane >> 2) & 1);
    float Aval0 = 0.f, Aval1 = 0.f;

    for (int it = 0; it < NITERS; ++it) {
        // ---- f phase: duals = Bf (complete by the wait just passed) ----
        STAGE(Bf + base);
        {
            float Sc = sumpassL(sx, sy, sd, rlocA, jh, lane, w, pcomb);
            Aval0 = LMU - __log2f(Sc);
            if (lane < 8 && jh == 0) DSTORE(&Af[base + rlocA + rr], Aval0);
        }
        {
            float Sc = sumpassL(sx, sy, sd, rlocB, jh, lane, w, pcomb);
            Aval1 = LMU - __log2f(Sc);
            if (lane < 8 && jh == 0) DSTORE(&Af[base + rlocB + rr], Aval1);
        }
        POSTB(2 * it + 2);
        WAITB(2 * it + 2);
        // ---- g phase: duals = Af ----
        STAGE(Af + base);
        {
            float Sc = sumpassL(sy, sx, sd, rlocA, jh, lane, w, pcomb);
            if (lane < 8 && jh == 0)
                DSTORE(&Bf[base + rlocA + rr], LMU - __log2f(Sc));
        }
        {
            float Sc = sumpassL(sy, sx, sd, rlocB, jh, lane, w, pcomb);
            if (lane < 8 && jh == 0)
                DSTORE(&Bf[base + rlocB + rr], LMU - __log2f(Sc));
        }
        POSTB(2 * it + 3);
        WAITB(2 * it + 3);
    }
    // last WAITB guarantees final Bf of the whole batch is complete

    // ---- epilogue: own 128 rows, own j-half per wave ----
    {
        float s = epilA(sx, sy, Bf + base, Aval0, rlocA, jh, lane)
                + epilA(sx, sy, Bf + base, Aval1, rlocB, jh, lane);
        #pragma unroll
        for (int m = 32; m > 0; m >>= 1) s += __shfl_xor(s, m, 64);
        if (lane == 0) wsum[w] = s;
        __syncthreads();
        if (tid == 0) {
            float t = 0.f;
            #pragma unroll
            for (int i = 0; i < 16; ++i) t += wsum[i];
            atomicAdd(out, t * (1.0f / (float)BB));
        }
    }
    #undef WAITB
    #undef POSTB
    #undef STAGE
}

// =============== verified R9 kernel (2812 us) as launch fallback ===============
__global__ __launch_bounds__(1024, 4) void emd_sinkhornS(
    const float* __restrict__ x, const float* __restrict__ y,
    float* __restrict__ Af, float* __restrict__ Bf,
    int* __restrict__ flags, float* __restrict__ out)
{
    extern __shared__ float S[];     // 128 KB
    __shared__ float pcomb[16 * 8];
    __shared__ float wsum[16];

    const int tid  = threadIdx.x;
    const int lane = tid & 63;
    const int w    = tid >> 6;
    const int pr   = w >> 1;
    const int jh   = w & 1;
    const int blk  = blockIdx.x;
    const int pair = blk & 7;
    const int q    = blk >> 3;
    const int b0   = pair * 2, b1 = b0 + 1;
    const int base0 = b0 * NN, base1 = b1 * NN;
    const int rloc  = q * 64 + pr * 8;
    int* fp = flags + 8192/4 + pair * 128;   // upper region of flag ws

    v4f *sy0 = (v4f*)S;
    v4f *sx0 = (v4f*)S + 1*NN;
    v4f *sy1 = (v4f*)S + 2*NN;
    v4f *sx1 = (v4f*)S + 3*NN;

    #pragma unroll
    for (int v = 0; v < 2; ++v) {
        const int p = tid + (v << 10);
        {
            const float* px = x + 3 * (size_t)(base0 + p);
            sx0[p] = (v4f){TWO_K2E * px[0], TWO_K2E * px[1], TWO_K2E * px[2], 0.f};
            const float* py = y + 3 * (size_t)(base0 + p);
            sy0[p] = (v4f){TWO_K2E * py[0], TWO_K2E * py[1], TWO_K2E * py[2], 0.f};
        }
        {
            const float* px = x + 3 * (size_t)(base1 + p);
            sx1[p] = (v4f){TWO_K2E * px[0], TWO_K2E * px[1], TWO_K2E * px[2], 0.f};
            const float* py = y + 3 * (size_t)(base1 + p);
            sy1[p] = (v4f){TWO_K2E * py[0], TWO_K2E * py[1], TWO_K2E * py[2], 0.f};
        }
    }
    if (tid < 128) {
        const int bb  = tid >> 6;
        const int col = q * 64 + (tid & 63);
        const int bs  = bb ? base1 : base0;
        const float* py = y + 3 * (size_t)(bs + col);
        const float a = py[0], b = py[1], c = py[2];
        DSTORE(&Bf[bs + col], -K2E * (a*a + b*b + c*c));
    }
    __syncthreads();
    if (tid == 0)
        __hip_atomic_store(fp + q * 4, 1, __ATOMIC_RELEASE, __HIP_MEMORY_SCOPE_AGENT);

    #define PW(pval, tgt) do { __syncthreads();                                 \
        if (tid == 0)                                                           \
            __hip_atomic_store(fp + q * 4, (pval), __ATOMIC_RELEASE,            \
                               __HIP_MEMORY_SCOPE_AGENT);                       \
        if (w == 0) {                                                           \
            for (;;) {                                                          \
                int vv = (lane < 32)                                            \
                    ? __hip_atomic_load(fp + lane * 4, __ATOMIC_RELAXED,        \
                                        __HIP_MEMORY_SCOPE_AGENT)               \
                    : 0x7fffffff;                                               \
                if (__ballot(vv >= (tgt)) == ~0ULL) break;                      \
                __builtin_amdgcn_s_sleep(1);                                    \
            }                                                                   \
        }                                                                       \
        __syncthreads(); } while (0)

    PW(1, 1);

    const int rr = ((lane & 1) << 2) | (lane & 2) | ((lane >> 2) & 1);
    float Aval0 = 0.f, Aval1 = 0.f;

    for (int it = 0; it < NITERS; ++it) {
        {
            float Sc = sumpassA(sx0, sy0, Bf + base0, rloc, jh, lane, w, pcomb);
            Aval0 = LMU - __log2f(Sc);
            if (lane < 8 && jh == 0) DSTORE(&Af[base0 + rloc + rr], Aval0);
        }
        {
            float Sc = sumpassA(sx1, sy1, Bf + base1, rloc, jh, lane, w, pcomb);
            Aval1 = LMU - __log2f(Sc);
            if (lane < 8 && jh == 0) DSTORE(&Af[base1 + rloc + rr], Aval1);
        }
        PW(2 * it + 2, 2 * it + 2);
        {
            float Sc = sumpassA(sy0, sx0, Af + base0, rloc, jh, lane, w, pcomb);
            if (lane < 8 && jh == 0)
                DSTORE(&Bf[base0 + rloc + rr], LMU - __log2f(Sc));
        }
        {
            float Sc = sumpassA(sy1, sx1, Af + base1, rloc, jh, lane, w, pcomb);
            if (lane < 8 && jh == 0)
                DSTORE(&Bf[base1 + rloc + rr], LMU - __log2f(Sc));
        }
        PW(2 * it + 3, 2 * it + 3);
    }

    {
        float s = epilA(sx0, sy0, Bf + base0, Aval0, rloc, jh, lane)
                + epilA(sx1, sy1, Bf + base1, Aval1, rloc, jh, lane);
        #pragma unroll
        for (int m = 32; m > 0; m >>= 1) s += __shfl_xor(s, m, 64);
        if (lane == 0) wsum[w] = s;
        __syncthreads();
        if (tid == 0) {
            float t = 0.f;
            #pragma unroll
            for (int i = 0; i < 16; ++i) t += wsum[i];
            atomicAdd(out, t * (1.0f / (float)BB));
        }
    }
    #undef PW
}

extern "C" void kernel_launch(void* const* d_in, const int* in_sizes, int n_in,
                              void* d_out, int out_size, void* d_ws, size_t ws_size,
                              hipStream_t stream) {
    const float* x = (const float*)d_in[0];
    const float* y = (const float*)d_in[1];
    float* out = (float*)d_out;
    char* ws = (char*)d_ws;

    int*   flags = (int*)ws;                                 // 16 KB (T: lower 4 KB; S: upper)
    float* Af    = (float*)(ws + 16384);                     // 128 KB
    float* Bf    = (float*)(ws + 16384 + (size_t)BB*NN*sizeof(float));

    hipMemsetAsync(flags, 0, 16384, stream);
    hipMemsetAsync(out, 0, sizeof(float), stream);

    void* args[] = {(void*)&x, (void*)&y, (void*)&Af, (void*)&Bf,
                    (void*)&flags, (void*)&out};

    // Preferred: one-batch/16-group/LDS-dual kernel (72 KB LDS).
    const size_t shmemT = (size_t)(2 * NN * 4 + NN) * sizeof(float);  // 72 KB
    hipError_t et = hipFuncSetAttribute((const void*)emd_sinkhornT,
                        hipFuncAttributeMaxDynamicSharedMemorySize, (int)shmemT);
    hipError_t e = (et == hipSuccess)
        ? hipLaunchCooperativeKernel((const void*)emd_sinkhornT,
                                     dim3(256), dim3(1024), args, shmemT, stream)
        : hipErrorInvalidValue;
    if (e != hipSuccess) {
        // Fallback: verified R9 kernel (2812 us, 128 KB LDS)
        const size_t shmemS = (size_t)4 * NN * 4 * sizeof(float);
        hipError_t es = hipFuncSetAttribute((const void*)emd_sinkhornS,
                            hipFuncAttributeMaxDynamicSharedMemorySize, (int)shmemS);
        hipError_t e2 = (es == hipSuccess)
            ? hipLaunchCooperativeKernel((const void*)emd_sinkhornS,
                                         dim3(256), dim3(1024), args, shmemS, stream)
            : hipErrorInvalidValue;
        if (e2 != hipSuccess) {
            hipLaunchKernelGGL(emd_sinkhornS, dim3(256), dim3(1024), shmemS,
                               stream, x, y, Af, Bf, flags, out);
        }
    }
}

// Round 11
// 2336.813 us; speedup vs baseline: 2.0649x; 1.0671x over previous
//
#include <hip/hip_runtime.h>

#define BB 16
#define NN 2048
#define NITERS 100

// k = log2(e)/eps, eps = 0.05
#define K2E      28.853900817779268f
#define TWO_K2E  57.707801635558536f
#define INV2K    0.017328679513998632f   // 1/(2k)
#define INV_K2E  0.034657359027997264f
#define INV4K    0.008664339756999316f   // 1/(4k)
#define LMU      (-11.0f)                // log2(1/2048)

#if __has_builtin(__builtin_amdgcn_exp2f)
#define EXP2F(x) __builtin_amdgcn_exp2f(x)
#else
#define EXP2F(x) exp2f(x)
#endif

typedef float v2f __attribute__((ext_vector_type(2)));
typedef float v4f __attribute__((ext_vector_type(4)));

// device-coherent (LLC-homed) accessors for the dual arrays
#define DSTORE(p, v) __hip_atomic_store((p), (v), __ATOMIC_RELAXED, __HIP_MEMORY_SCOPE_AGENT)
#define DLOAD(p)     __hip_atomic_load((p), __ATOMIC_RELAXED, __HIP_MEMORY_SCOPE_AGENT)

// verified multi-value butterfly: 8 partials -> full row-sum on lanes 0..7
// at row index rr = ((lane&1)<<2)|(lane&2)|((lane>>2)&1)
__device__ __forceinline__ float bfly8(const float acc[8], int lane) {
    const bool b0 = lane & 1, b1 = lane & 2, b2 = lane & 4;
    float v4[4], v2_[2], v1;
    #pragma unroll
    for (int i = 0; i < 4; ++i) {
        float recv = __shfl_xor(b0 ? acc[i] : acc[i+4], 1, 64);
        v4[i] = (b0 ? acc[i+4] : acc[i]) + recv;
    }
    #pragma unroll
    for (int i = 0; i < 2; ++i) {
        float recv = __shfl_xor(b1 ? v4[i] : v4[i+2], 2, 64);
        v2_[i] = (b1 ? v4[i+2] : v4[i]) + recv;
    }
    {
        float recv = __shfl_xor(b2 ? v2_[0] : v2_[1], 4, 64);
        v1 = (b2 ? v2_[1] : v2_[0]) + recv;
    }
    v1 += __shfl_xor(v1, 8, 64);
    v1 += __shfl_xor(v1, 16, 64);
    v1 += __shfl_xor(v1, 32, 64);
    return v1;
}

// R22 FULL-J sum-pass: each wave owns 8 rows x ALL 2048 j. Summation order
// identical to R3's verified full-j pass (absmax 0.0). dv comes from the
// per-phase LDS dual buffer on the fly (no dv[32] register preload — the
// spill that killed R3's version). No pcomb, no barrier: the butterfly
// alone yields complete row sums on lanes 0..7.
__device__ __forceinline__ float sumpassF(
    const v4f* __restrict__ U, const v4f* __restrict__ T,
    const float* __restrict__ sdv,   // LDS dual buffer [0..NN)
    int rloc, int lane)
{
    v2f xp0[4], xp1[4], xp2[4], acc2[4];
    #pragma unroll
    for (int p = 0; p < 4; ++p) {
        const v4f ua = U[rloc + 2*p];
        const v4f ub = U[rloc + 2*p + 1];
        xp0[p] = (v2f){ua.x * INV2K, ub.x * INV2K};
        xp1[p] = (v2f){ua.y * INV2K, ub.y * INV2K};
        xp2[p] = (v2f){ua.z * INV2K, ub.z * INV2K};
        acc2[p] = (v2f){0.f, 0.f};
    }
    #pragma unroll 4
    for (int s = 0; s < 32; ++s) {
        const int p = lane + (s << 6);
        const v4f t = T[p];
        const float ad = sdv[p];
        const v2f a0v = (v2f){t.x, t.x}, a1v = (v2f){t.y, t.y};
        const v2f a2v = (v2f){t.z, t.z}, adv = (v2f){ad, ad};
        #pragma unroll
        for (int qq = 0; qq < 4; ++qq) {
            v2f d = __builtin_elementwise_fma(xp0[qq], a0v,
                    __builtin_elementwise_fma(xp1[qq], a1v,
                    __builtin_elementwise_fma(xp2[qq], a2v, adv)));
            acc2[qq] += (v2f){EXP2F(d.x), EXP2F(d.y)};
        }
    }
    float acc[8];
    #pragma unroll
    for (int p = 0; p < 4; ++p) { acc[2*p] = acc2[p].x; acc[2*p+1] = acc2[p].y; }
    return bfly8(acc, lane);   // lanes<8: full row-sum for row rloc + rr
}

// R10-verified sum-pass with LDS duals + j-half split (fallback kernel).
__device__ __forceinline__ float sumpassL(
    const v4f* __restrict__ U, const v4f* __restrict__ T,
    const float* __restrict__ sdv,
    int rloc, int jh, int lane, int w, float* pcomb)
{
    const int jb = (jh << 10) + lane;
    float dv[16];
    #pragma unroll
    for (int s = 0; s < 16; ++s)
        dv[s] = sdv[jb + (s << 6)];

    v2f xp0[4], xp1[4], xp2[4], acc2[4];
    #pragma unroll
    for (int p = 0; p < 4; ++p) {
        const v4f ua = U[rloc + 2*p];
        const v4f ub = U[rloc + 2*p + 1];
        xp0[p] = (v2f){ua.x * INV2K, ub.x * INV2K};
        xp1[p] = (v2f){ua.y * INV2K, ub.y * INV2K};
        xp2[p] = (v2f){ua.z * INV2K, ub.z * INV2K};
        acc2[p] = (v2f){0.f, 0.f};
    }
    #pragma unroll 4
    for (int s = 0; s < 16; ++s) {
        const v4f t = T[jb + (s << 6)];
        const float ad = dv[s];
        const v2f a0v = (v2f){t.x, t.x}, a1v = (v2f){t.y, t.y};
        const v2f a2v = (v2f){t.z, t.z}, adv = (v2f){ad, ad};
        #pragma unroll
        for (int qq = 0; qq < 4; ++qq) {
            v2f d = __builtin_elementwise_fma(xp0[qq], a0v,
                    __builtin_elementwise_fma(xp1[qq], a1v,
                    __builtin_elementwise_fma(xp2[qq], a2v, adv)));
            acc2[qq] += (v2f){EXP2F(d.x), EXP2F(d.y)};
        }
    }
    float acc[8];
    #pragma unroll
    for (int p = 0; p < 4; ++p) { acc[2*p] = acc2[p].x; acc[2*p+1] = acc2[p].y; }
    float v1 = bfly8(acc, lane);
    const int rr = ((lane & 1) << 2) | (lane & 2) | ((lane >> 2) & 1);
    if (lane < 8) pcomb[w * 8 + rr] = v1;
    __syncthreads();
    float Sc = 0.f;
    if (lane < 8) Sc = v1 + pcomb[(w ^ 1) * 8 + rr];
    return Sc;
}

// Epilogue partial: sum_j P_ij*C_ij, 8 rows x one j-half; AoS tables.
// (verified; R3 verified the two-jh-call full-j composition)
__device__ __forceinline__ float epilA(
    const v4f* __restrict__ U, const v4f* __restrict__ T,
    const float* __restrict__ gB,
    float Aval, int rloc, int jh, int lane)
{
    const int jb = (jh << 10) + lane;
    float dv[16];
    #pragma unroll
    for (int s = 0; s < 16; ++s)
        dv[s] = DLOAD(gB + jb + (s << 6));

    float xr0[8], xr1[8], xr2[8], Ak[8], x2k[8];
    #pragma unroll
    for (int k = 0; k < 8; ++k) {
        const v4f u = U[rloc + k];
        xr0[k] = u.x * INV2K;
        xr1[k] = u.y * INV2K;
        xr2[k] = u.z * INV2K;
        const int src = ((k & 1) << 2) | (k & 2) | ((k >> 2) & 1);
        Ak[k]  = __shfl(Aval, src, 64);
        x2k[k] = K2E * (xr0[k]*xr0[k] + xr1[k]*xr1[k] + xr2[k]*xr2[k]);
    }
    float acc = 0.f;
    for (int s = 0; s < 16; ++s) {
        const v4f t = T[jb + (s << 6)];
        const float a0 = t.x, a1 = t.y, a2 = t.z, tb = dv[s];
        const float q2 = (a0*a0 + a1*a1 + a2*a2) * INV4K;   // k|y|^2
        #pragma unroll
        for (int k = 0; k < 8; ++k) {
            float d = fmaf(xr0[k], a0, fmaf(xr1[k], a1, fmaf(xr2[k], a2, tb)));
            float P = EXP2F(d + Ak[k]);                       // exp(logP)
            float C = fmaxf((x2k[k] + q2 - (d - tb)) * INV_K2E, 0.f);
            acc = fmaf(P, C, acc);
        }
    }
    return acc;
}

// R22: one batch/block, 16-block groups, LDS duals (all R10-proven), plus
// FULL-J single pass per phase: wave w owns rows q*128 + w*8 .. +8 x all j.
// Per phase: wait -> stage -> ONE pass -> post. Barriers/phase 6 -> 4,
// one pass-startup ramp instead of two, pcomb combine eliminated.
__global__ __launch_bounds__(1024, 4) void emd_sinkhornU(
    const float* __restrict__ x, const float* __restrict__ y,
    float* __restrict__ Af, float* __restrict__ Bf,
    int* __restrict__ flags, float* __restrict__ out)
{
    extern __shared__ float S[];     // sy(32KB) | sx(32KB) | sd(8KB) = 72 KB
    __shared__ float wsum[16];

    const int tid  = threadIdx.x;
    const int lane = tid & 63;
    const int w    = tid >> 6;        // 0..15
    const int blk  = blockIdx.x;
    const int b    = blk >> 4;        // batch 0..15
    const int q    = blk & 15;        // row-slab within batch (128 rows)
    const int base = b * NN;
    const int row0 = q * 128;
    const int rloc = row0 + w * 8;    // wave-owned 8 rows
    int* fb = flags + b * 64;         // 16 slots x 16 B per batch

    v4f   *sy = (v4f*)S;              // batch y (2k-scaled, AoS)
    v4f   *sx = (v4f*)S + NN;         // batch x
    float *sd = (float*)((v4f*)S + 2 * NN);   // staged duals [NN]

    // ---- prologue: stage 2k-scaled AoS tables for own batch ----
    #pragma unroll
    for (int v = 0; v < 2; ++v) {
        const int p = tid + (v << 10);
        const float* px = x + 3 * (size_t)(base + p);
        sx[p] = (v4f){TWO_K2E * px[0], TWO_K2E * px[1], TWO_K2E * px[2], 0.f};
        const float* py = y + 3 * (size_t)(base + p);
        sy[p] = (v4f){TWO_K2E * py[0], TWO_K2E * py[1], TWO_K2E * py[2], 0.f};
    }
    // ---- prologue: B0-init for own 128 columns ----
    if (tid < 128) {
        const int col = row0 + tid;
        const float* py = y + 3 * (size_t)(base + col);
        const float a = py[0], bb = py[1], c = py[2];
        DSTORE(&Bf[base + col], -K2E * (a*a + bb*bb + c*c));
    }
    __syncthreads();                  // drains table + B-init stores
    if (tid == 0)
        __hip_atomic_store(fb + q * 4, 1, __ATOMIC_RELEASE, __HIP_MEMORY_SCOPE_AGENT);

    // wait: all 16 blocks of own batch posted >= tgt (wave 0 polls)
    #define WAITB(tgt) do { __syncthreads();                                    \
        if (w == 0) {                                                           \
            for (;;) {                                                          \
                int vv = (lane < 16)                                            \
                    ? __hip_atomic_load(fb + lane * 4, __ATOMIC_RELAXED,        \
                                        __HIP_MEMORY_SCOPE_AGENT)               \
                    : 0x7fffffff;                                               \
                if (__ballot(vv >= (tgt)) == ~0ULL) break;                      \
                __builtin_amdgcn_s_sleep(1);                                    \
            }                                                                   \
        }                                                                       \
        __syncthreads(); } while (0)

    // post: entry barrier drains DSTOREs (compiler emits vmcnt(0) before
    // s_barrier), then tid0 release-stores the phase value.
    #define POSTB(pval) do { __syncthreads();                                   \
        if (tid == 0)                                                           \
            __hip_atomic_store(fb + q * 4, (pval), __ATOMIC_RELEASE,            \
                               __HIP_MEMORY_SCOPE_AGENT);                       \
    } while (0)

    // stage one dual array (LLC, coherent DLOAD) into sd[0..NN)
    #define STAGE(gsrc) do {                                                    \
        float t0_ = DLOAD((gsrc) + tid);                                        \
        float t1_ = DLOAD((gsrc) + tid + 1024);                                 \
        sd[tid] = t0_; sd[tid + 1024] = t1_;                                    \
        __syncthreads(); } while (0)

    WAITB(1);                         // all B-inits of the batch visible

    const int rr = ((lane & 1) << 2) | (lane & 2) | ((lane >> 2) & 1);
    float Aval = 0.f;

    for (int it = 0; it < NITERS; ++it) {
        // ---- f phase: duals = Bf (complete by the wait just passed) ----
        STAGE(Bf + base);
        {
            float v1 = sumpassF(sx, sy, sd, rloc, lane);
            Aval = LMU - __log2f(v1);
            if (lane < 8) DSTORE(&Af[base + rloc + rr], Aval);
        }
        POSTB(2 * it + 2);
        WAITB(2 * it + 2);
        // ---- g phase: duals = Af ----
        STAGE(Af + base);
        {
            float v1 = sumpassF(sy, sx, sd, rloc, lane);
            if (lane < 8)
                DSTORE(&Bf[base + rloc + rr], LMU - __log2f(v1));
        }
        POSTB(2 * it + 3);
        WAITB(2 * it + 3);
    }
    // last WAITB guarantees final Bf of the whole batch is complete

    // ---- epilogue: wave-owned 8 rows x full j (R3-verified composition) ----
    {
        float s = epilA(sx, sy, Bf + base, Aval, rloc, 0, lane)
                + epilA(sx, sy, Bf + base, Aval, rloc, 1, lane);
        #pragma unroll
        for (int m = 32; m > 0; m >>= 1) s += __shfl_xor(s, m, 64);
        if (lane == 0) wsum[w] = s;
        __syncthreads();
        if (tid == 0) {
            float t = 0.f;
            #pragma unroll
            for (int i = 0; i < 16; ++i) t += wsum[i];
            atomicAdd(out, t * (1.0f / (float)BB));
        }
    }
    #undef WAITB
    #undef POSTB
    #undef STAGE
}

// =============== verified R10 kernel (2494 us) as launch fallback ===============
__global__ __launch_bounds__(1024, 4) void emd_sinkhornT(
    const float* __restrict__ x, const float* __restrict__ y,
    float* __restrict__ Af, float* __restrict__ Bf,
    int* __restrict__ flags, float* __restrict__ out)
{
    extern __shared__ float S[];     // 72 KB
    __shared__ float pcomb[16 * 8];
    __shared__ float wsum[16];

    const int tid  = threadIdx.x;
    const int lane = tid & 63;
    const int w    = tid >> 6;
    const int pr   = w >> 1;
    const int jh   = w & 1;
    const int blk  = blockIdx.x;
    const int b    = blk >> 4;
    const int q    = blk & 15;
    const int base = b * NN;
    const int row0 = q * 128;
    const int rlocA = row0 + pr * 8;
    const int rlocB = row0 + 64 + pr * 8;
    int* fb = flags + b * 64;

    v4f   *sy = (v4f*)S;
    v4f   *sx = (v4f*)S + NN;
    float *sd = (float*)((v4f*)S + 2 * NN);

    #pragma unroll
    for (int v = 0; v < 2; ++v) {
        const int p = tid + (v << 10);
        const float* px = x + 3 * (size_t)(base + p);
        sx[p] = (v4f){TWO_K2E * px[0], TWO_K2E * px[1], TWO_K2E * px[2], 0.f};
        const float* py = y + 3 * (size_t)(base + p);
        sy[p] = (v4f){TWO_K2E * py[0], TWO_K2E * py[1], TWO_K2E * py[2], 0.f};
    }
    if (tid < 128) {
        const int col = row0 + tid;
        const float* py = y + 3 * (size_t)(base + col);
        const float a = py[0], bb = py[1], c = py[2];
        DSTORE(&Bf[base + col], -K2E * (a*a + bb*bb + c*c));
    }
    __syncthreads();
    if (tid == 0)
        __hip_atomic_store(fb + q * 4, 1, __ATOMIC_RELEASE, __HIP_MEMORY_SCOPE_AGENT);

    #define WAITB2(tgt) do { __syncthreads();                                   \
        if (w == 0) {                                                           \
            for (;;) {                                                          \
                int vv = (lane < 16)                                            \
                    ? __hip_atomic_load(fb + lane * 4, __ATOMIC_RELAXED,        \
                                        __HIP_MEMORY_SCOPE_AGENT)               \
                    : 0x7fffffff;                                               \
                if (__ballot(vv >= (tgt)) == ~0ULL) break;                      \
                __builtin_amdgcn_s_sleep(1);                                    \
            }                                                                   \
        }                                                                       \
        __syncthreads(); } while (0)

    #define POSTB2(pval) do { __syncthreads();                                  \
        if (tid == 0)                                                           \
            __hip_atomic_store(fb + q * 4, (pval), __ATOMIC_RELEASE,            \
                               __HIP_MEMORY_SCOPE_AGENT);                       \
    } while (0)

    #define STAGE2(gsrc) do {                                                   \
        float t0_ = DLOAD((gsrc) + tid);                                        \
        float t1_ = DLOAD((gsrc) + tid + 1024);                                 \
        sd[tid] = t0_; sd[tid + 1024] = t1_;                                    \
        __syncthreads(); } while (0)

    WAITB2(1);

    const int rr = ((lane & 1) << 2) | (lane & 2) | ((lane >> 2) & 1);
    float Aval0 = 0.f, Aval1 = 0.f;

    for (int it = 0; it < NITERS; ++it) {
        STAGE2(Bf + base);
        {
            float Sc = sumpassL(sx, sy, sd, rlocA, jh, lane, w, pcomb);
            Aval0 = LMU - __log2f(Sc);
            if (lane < 8 && jh == 0) DSTORE(&Af[base + rlocA + rr], Aval0);
        }
        {
            float Sc = sumpassL(sx, sy, sd, rlocB, jh, lane, w, pcomb);
            Aval1 = LMU - __log2f(Sc);
            if (lane < 8 && jh == 0) DSTORE(&Af[base + rlocB + rr], Aval1);
        }
        POSTB2(2 * it + 2);
        WAITB2(2 * it + 2);
        STAGE2(Af + base);
        {
            float Sc = sumpassL(sy, sx, sd, rlocA, jh, lane, w, pcomb);
            if (lane < 8 && jh == 0)
                DSTORE(&Bf[base + rlocA + rr], LMU - __log2f(Sc));
        }
        {
            float Sc = sumpassL(sy, sx, sd, rlocB, jh, lane, w, pcomb);
            if (lane < 8 && jh == 0)
                DSTORE(&Bf[base + rlocB + rr], LMU - __log2f(Sc));
        }
        POSTB2(2 * it + 3);
        WAITB2(2 * it + 3);
    }

    {
        float s = epilA(sx, sy, Bf + base, Aval0, rlocA, jh, lane)
                + epilA(sx, sy, Bf + base, Aval1, rlocB, jh, lane);
        #pragma unroll
        for (int m = 32; m > 0; m >>= 1) s += __shfl_xor(s, m, 64);
        if (lane == 0) wsum[w] = s;
        __syncthreads();
        if (tid == 0) {
            float t = 0.f;
            #pragma unroll
            for (int i = 0; i < 16; ++i) t += wsum[i];
            atomicAdd(out, t * (1.0f / (float)BB));
        }
    }
    #undef WAITB2
    #undef POSTB2
    #undef STAGE2
}

extern "C" void kernel_launch(void* const* d_in, const int* in_sizes, int n_in,
                              void* d_out, int out_size, void* d_ws, size_t ws_size,
                              hipStream_t stream) {
    const float* x = (const float*)d_in[0];
    const float* y = (const float*)d_in[1];
    float* out = (float*)d_out;
    char* ws = (char*)d_ws;

    int*   flags = (int*)ws;                                 // 16 x 16 x 16 B = 4 KB (shared region; only one kernel launches)
    float* Af    = (float*)(ws + 16384);                     // 128 KB
    float* Bf    = (float*)(ws + 16384 + (size_t)BB*NN*sizeof(float));

    hipMemsetAsync(flags, 0, 16384, stream);
    hipMemsetAsync(out, 0, sizeof(float), stream);

    void* args[] = {(void*)&x, (void*)&y, (void*)&Af, (void*)&Bf,
                    (void*)&flags, (void*)&out};

    const size_t shmem = (size_t)(2 * NN * 4 + NN) * sizeof(float);  // 72 KB
    hipError_t eu = hipFuncSetAttribute((const void*)emd_sinkhornU,
                        hipFuncAttributeMaxDynamicSharedMemorySize, (int)shmem);
    hipError_t e = (eu == hipSuccess)
        ? hipLaunchCooperativeKernel((const void*)emd_sinkhornU,
                                     dim3(256), dim3(1024), args, shmem, stream)
        : hipErrorInvalidValue;
    if (e != hipSuccess) {
        // Fallback: verified R10 kernel (2494 us)
        hipError_t et = hipFuncSetAttribute((const void*)emd_sinkhornT,
                            hipFuncAttributeMaxDynamicSharedMemorySize, (int)shmem);
        hipError_t e2 = (et == hipSuccess)
            ? hipLaunchCooperativeKernel((const void*)emd_sinkhornT,
                                         dim3(256), dim3(1024), args, shmem, stream)
            : hipErrorInvalidValue;
        if (e2 != hipSuccess) {
            hipLaunchKernelGGL(emd_sinkhornT, dim3(256), dim3(1024), shmem,
                               stream, x, y, Af, Bf, flags, out);
        }
    }
}